// Round 1
// baseline (249.052 us; speedup 1.0000x reference)
//
#include <hip/hip_runtime.h>

// Problem constants (from reference)
#define NB   8
#define AB   256
#define HB   128
#define WB   128
#define CB   19
#define CP1  20
#define PLANE (HB*WB)          // 16384
#define NPIX  (NB*PLANE)       // 131072

// ---------------------------------------------------------------------------
// Kernel A: nearest-neighbor label downsample -> u8 labels, plus class counts
// ---------------------------------------------------------------------------
__global__ __launch_bounds__(256) void k_labels(const int* __restrict__ target,
                                                unsigned char* __restrict__ labels,
                                                float* __restrict__ counts) {
    __shared__ int hist[CP1];
    int tid = threadIdx.x;
    if (tid < CP1) hist[tid] = 0;
    __syncthreads();

    int p = blockIdx.x * 256 + tid;          // p in [0, NPIX)
    int n   = p >> 14;                       // /16384
    int rem = p & 16383;
    int h   = rem >> 7;
    int w   = rem & 127;
    // src idx: target[n, h*8, w*8], target is [N,1024,1024]
    size_t idx = (size_t)n * 1048576 + (size_t)h * 8192 + (size_t)w * 8;
    int l = target[idx];
    labels[p] = (unsigned char)l;
    int lab0 = (l == 255) ? 0 : l;
    if (lab0 < 0 || lab0 >= CP1) lab0 = 0;   // safety clamp
    atomicAdd(&hist[lab0], 1);
    __syncthreads();
    if (tid < CP1) atomicAdd(&counts[tid], (float)hist[tid]);
}

// ---------------------------------------------------------------------------
// Kernel B: per-class, per-channel sum and sum-of-squares over features.
// One block per (n, a) plane. Race-free LDS: acc[class][tid] (sum,sq) pairs.
// ---------------------------------------------------------------------------
__global__ __launch_bounds__(256) void k_stats(const float* __restrict__ features,
                                               const unsigned char* __restrict__ labels,
                                               float* __restrict__ gsum,
                                               float* __restrict__ gsq) {
    __shared__ float acc[CP1 * 256 * 2];     // 40 KB
    int tid = threadIdx.x;
    int a = blockIdx.x & 255;
    int n = blockIdx.x >> 8;

    for (int i = tid; i < CP1 * 256 * 2; i += 256) acc[i] = 0.f;
    __syncthreads();

    const float* fbase = features + ((size_t)(n * AB + a)) * PLANE;
    const unsigned char* lbase = labels + (size_t)n * PLANE;

    #pragma unroll 4
    for (int it = 0; it < 16; ++it) {
        int pix = it * 1024 + tid * 4;
        float4 f = *reinterpret_cast<const float4*>(fbase + pix);
        unsigned int lw = *reinterpret_cast<const unsigned int*>(lbase + pix);
        float fa[4] = {f.x, f.y, f.z, f.w};
        #pragma unroll
        for (int j = 0; j < 4; ++j) {
            int l = (lw >> (8 * j)) & 255;
            int lab0 = (l == 255) ? 0 : (l < CP1 ? l : 0);
            int b = (lab0 * 256 + tid) * 2;
            float v = fa[j];
            acc[b]     += v;
            acc[b + 1] += v * v;
        }
    }
    __syncthreads();

    // tree-reduce the 256 per-thread columns, all 20 classes at once
    #pragma unroll
    for (int off = 128; off >= 1; off >>= 1) {
        for (int idx = tid; idx < CP1 * off; idx += 256) {
            int l = idx / off;
            int j = idx - l * off;
            int b0 = (l * 256 + j) * 2;
            int b1 = (l * 256 + j + off) * 2;
            acc[b0]     += acc[b1];
            acc[b0 + 1] += acc[b1 + 1];
        }
        __syncthreads();
    }

    if (tid < CP1) {
        atomicAdd(&gsum[tid * 256 + a], acc[tid * 512]);
        atomicAdd(&gsq [tid * 256 + a], acc[tid * 512 + 1]);
    }
}

// ---------------------------------------------------------------------------
// Kernel C: ave/var/new_cov  ->  sigma2 lookup table [CP1][CB]
// One block per label l, thread t = channel a.
// ---------------------------------------------------------------------------
__global__ __launch_bounds__(256) void k_table(const float* __restrict__ counts,
                                               const float* __restrict__ gsum,
                                               const float* __restrict__ gsq,
                                               const float* __restrict__ fcw,
                                               const float* __restrict__ Ave,
                                               const float* __restrict__ CoV,
                                               const float* __restrict__ Amount,
                                               const int* __restrict__ ratio_p,
                                               float* __restrict__ table) {
    __shared__ float ncov_s[256];
    __shared__ float wl_s[256];
    __shared__ float red[4];
    int t = threadIdx.x;
    int l = blockIdx.x;

    float cnt  = counts[l];
    float cntc = (cnt == 0.f) ? 1.f : cnt;
    float sum  = gsum[l * 256 + t];
    float sq   = gsq [l * 256 + t];
    float ave  = sum / cntc;
    float var  = sq / cntc - ave * ave;      // == ref two-pass form exactly (fp32 algebra)
    float denom = cnt + Amount[l];
    float wcv  = (denom > 0.f) ? cnt / denom : 0.f;
    float d0   = Ave[l * 256 + t] - ave;
    float ncov = CoV[l * 256 + t] * (1.f - wcv) + var * wcv + wcv * (1.f - wcv) * d0 * d0;

    ncov_s[t] = ncov;
    int lw = (l < CB) ? l : (CB - 1);        // l==19 row never used (labels < 19)
    wl_s[t] = fcw[lw * 256 + t];
    __syncthreads();

    float ratio_f = (float)(*ratio_p);
    for (int c = 0; c < CB; ++c) {
        float dv = fcw[c * 256 + t] - wl_s[t];
        float r = ncov_s[t] * dv * dv;
        #pragma unroll
        for (int off = 32; off; off >>= 1) r += __shfl_down(r, off);
        if ((t & 63) == 0) red[t >> 6] = r;
        __syncthreads();
        if (t == 0) table[l * CB + c] = ratio_f * (red[0] + red[1] + red[2] + red[3]);
        __syncthreads();
    }
}

// ---------------------------------------------------------------------------
// Kernel D: out[n,c,h,w] = y[n,c,h,w] + 0.5 * table[lab[n,h,w]][c] * keep
// ---------------------------------------------------------------------------
__global__ __launch_bounds__(256) void k_apply(const float* __restrict__ y,
                                               const unsigned char* __restrict__ labels,
                                               const float* __restrict__ table,
                                               float* __restrict__ out) {
    __shared__ float tab[CP1 * CB];
    int tid = threadIdx.x;
    for (int i = tid; i < CP1 * CB; i += 256) tab[i] = table[i];
    __syncthreads();

    int b = blockIdx.x;
    int chunk = b & 3;
    int c = (b >> 2) % CB;
    int n = b / (4 * CB);

    const float* ybase = y + ((size_t)(n * CB + c)) * PLANE;
    float* obase = out + ((size_t)(n * CB + c)) * PLANE;
    const unsigned char* lbase = labels + (size_t)n * PLANE;

    #pragma unroll
    for (int it = 0; it < 4; ++it) {
        int pix = chunk * 4096 + it * 1024 + tid * 4;
        float4 yv = *reinterpret_cast<const float4*>(ybase + pix);
        unsigned int lw = *reinterpret_cast<const unsigned int*>(lbase + pix);
        float ya[4] = {yv.x, yv.y, yv.z, yv.w};
        float o[4];
        #pragma unroll
        for (int j = 0; j < 4; ++j) {
            int l = (lw >> (8 * j)) & 255;
            bool keep = (l != 255);
            int lab0 = keep ? (l < CP1 ? l : 0) : 0;
            float s = tab[lab0 * CB + c];
            o[j] = ya[j] + (keep ? 0.5f * s : 0.f);
        }
        *reinterpret_cast<float4*>(obase + pix) = make_float4(o[0], o[1], o[2], o[3]);
    }
}

// ---------------------------------------------------------------------------
extern "C" void kernel_launch(void* const* d_in, const int* in_sizes, int n_in,
                              void* d_out, int out_size, void* d_ws, size_t ws_size,
                              hipStream_t stream) {
    const float* features = (const float*)d_in[0];   // [8,256,128,128]
    const float* y        = (const float*)d_in[1];   // [8,19,128,128]
    const float* fcw      = (const float*)d_in[2];   // [19,256]
    const float* Ave      = (const float*)d_in[3];   // [20,256]
    const float* CoV      = (const float*)d_in[4];   // [20,256]
    const float* Amount   = (const float*)d_in[5];   // [20]
    const int*   target   = (const int*)d_in[6];     // [8,1024,1024]
    const int*   ratio    = (const int*)d_in[7];     // scalar

    char* ws = (char*)d_ws;
    float* counts = (float*)(ws + 0);                // 20 f32
    float* gsum   = (float*)(ws + 128);              // 20*256 f32
    float* gsq    = (float*)(ws + 20608);            // 20*256 f32
    unsigned char* labels = (unsigned char*)(ws + 41088);   // 131072 u8
    float* table  = (float*)(ws + 41088 + 131072);   // 20*19 f32
    float* out    = (float*)d_out;

    // zero the accumulators (ws is poisoned 0xAA before each launch)
    hipMemsetAsync(ws, 0, 41088, stream);

    k_labels<<<NPIX / 256, 256, 0, stream>>>(target, labels, counts);
    k_stats <<<NB * AB,     256, 0, stream>>>(features, labels, gsum, gsq);
    k_table <<<CP1,         256, 0, stream>>>(counts, gsum, gsq, fcw, Ave, CoV, Amount, ratio, table);
    k_apply <<<NB * CB * 4, 256, 0, stream>>>(y, labels, table, out);
}